// Round 1
// baseline (665.217 us; speedup 1.0000x reference)
//
#include <hip/hip_runtime.h>

typedef unsigned short u16;
typedef unsigned int u32;
typedef __attribute__((ext_vector_type(8))) short bf16x8;
typedef __attribute__((ext_vector_type(8))) u16 u16x8;
typedef __attribute__((ext_vector_type(4))) u16 u16x4;
typedef __attribute__((ext_vector_type(4))) float f32x4;

#define DEV static __device__ __forceinline__

DEV u16 f2bf(float f) {
    union { float f; u32 u; } v; v.f = f;
    u32 r = v.u + 0x7FFFu + ((v.u >> 16) & 1u);
    return (u16)(r >> 16);
}

DEV int swzc(int r, int c) { return c ^ ((r >> 1) & 3); }

DEV void gload_lds16(const void* g, void* l) {
    __builtin_amdgcn_global_load_lds((const __attribute__((address_space(1))) void*)g,
                                     (__attribute__((address_space(3))) void*)l, 16, 0, 0);
}

// C[M][N] = A[M][K] @ Bt[N][K]^T, row-major everything, K-contiguous operand tiles.
// BM=64 fixed. 256 threads = 4 waves, wave tile WM=32 x WN, waves 2x2.
// AF32/BF32: operand is fp32 in global -> reg-stage + cvt to bf16 (else bf16 via global_load_lds).
// DUMPA: write bf16 copy of A tile to Adump (same lda). BIAS: 0 none, 1 per-row, 2 per-col.
// OUTBF: bf16 output, else fp32 partial at Cp + s*M*N.
template<int BN, int WN, bool AF32, bool BF32, bool DUMPA, int BIAS, bool RELU, bool OUTBF>
__global__ __launch_bounds__(256, 3) void gemm_k(
    const void* __restrict__ Ap, const void* __restrict__ Bp, void* __restrict__ Cp,
    u16* __restrict__ Adump, const float* __restrict__ bias,
    int M, int N, int K, int lda, int ldb, int nRT, int nNT, int KCH)
{
    constexpr int BM = 64, WM = 32;
    constexpr int FI = WM / 16, FJ = WN / 16;
    constexpr int CPT = BN / 64;
    static_assert(BN == 2 * WN, "waves are 2x2");
    __shared__ u16 ldsA[2][BM * 32];
    __shared__ u16 ldsB[2][BN * 32];

    const int tid = threadIdx.x;
    int bid = blockIdx.x;
    const int rt = bid % nRT; bid /= nRT;
    const int nt = bid % nNT;
    const int s  = bid / nNT;
    const int m0 = rt * BM, n0 = nt * BN;
    const int kBeg = s * KCH;
    const int kEnd = (K < kBeg + KCH) ? K : (kBeg + KCH);
    const int nsteps = (kEnd - kBeg) >> 5;

    const int w = tid >> 6, l = tid & 63;
    const int wm = (w >> 1) * WM, wn = (w & 1) * WN;
    const int lr = l & 15, lg = l >> 4;

    f32x4 acc[FI][FJ] = {};
    float aR[8], bR[8];

    auto aIssue = [&](int buf, int k0) {
        if constexpr (AF32) {
            const float* A = (const float*)Ap;
            int r = tid >> 2, q = tid & 3;
            int gm = m0 + r; gm = (gm < M) ? gm : (M - 1);
            const float4* src = (const float4*)(A + (size_t)gm * lda + k0 + q * 8);
            float4 v0 = src[0], v1 = src[1];
            aR[0]=v0.x; aR[1]=v0.y; aR[2]=v0.z; aR[3]=v0.w;
            aR[4]=v1.x; aR[5]=v1.y; aR[6]=v1.z; aR[7]=v1.w;
        } else {
            const u16* A = (const u16*)Ap;
            int r = tid >> 2, cs = tid & 3;
            int c = swzc(r, cs);
            int gm = m0 + r; gm = (gm < M) ? gm : (M - 1);
            gload_lds16(A + (size_t)gm * lda + k0 + c * 8, &ldsA[buf][tid * 8]);
        }
    };
    auto aCommit = [&](int buf, int k0) {
        if constexpr (AF32) {
            int r = tid >> 2, q = tid & 3;
            u16x8 pk;
            #pragma unroll
            for (int e = 0; e < 8; e++) pk[e] = f2bf(aR[e]);
            *(u16x8*)&ldsA[buf][r * 32 + swzc(r, q) * 8] = pk;
            if constexpr (DUMPA) {
                int gm = m0 + r;
                if (gm < M) *(u16x8*)(Adump + (size_t)gm * lda + k0 + q * 8) = pk;
            }
        }
    };
    auto bIssue = [&](int buf, int k0) {
        if constexpr (BF32) {
            const float* B = (const float*)Bp;
            int r = tid >> 2, q = tid & 3;
            int gn = n0 + r; gn = (gn < N) ? gn : (N - 1);
            const float4* src = (const float4*)(B + (size_t)gn * ldb + k0 + q * 8);
            float4 v0 = src[0], v1 = src[1];
            bR[0]=v0.x; bR[1]=v0.y; bR[2]=v0.z; bR[3]=v0.w;
            bR[4]=v1.x; bR[5]=v1.y; bR[6]=v1.z; bR[7]=v1.w;
        } else {
            const u16* B = (const u16*)Bp;
            #pragma unroll
            for (int u = 0; u < CPT; u++) {
                int slot = u * 256 + tid;       // LDS dest = slot*16B (lane-stride 16 for gld_lds)
                int r = slot >> 2, cs = slot & 3;
                int c = swzc(r, cs);
                int gn = n0 + r; gn = (gn < N) ? gn : (N - 1);
                gload_lds16(B + (size_t)gn * ldb + k0 + c * 8, &ldsB[buf][slot * 8]);
            }
        }
    };
    auto bCommit = [&](int buf) {
        if constexpr (BF32) {
            int r = tid >> 2, q = tid & 3;
            u16x8 pk;
            #pragma unroll
            for (int e = 0; e < 8; e++) pk[e] = f2bf(bR[e]);
            *(u16x8*)&ldsB[buf][r * 32 + swzc(r, q) * 8] = pk;
        }
    };

    aIssue(0, kBeg); bIssue(0, kBeg);
    aCommit(0, kBeg); bCommit(0);
    __syncthreads();

    for (int t = 0; t < nsteps; t++) {
        const int k = kBeg + t * 32;
        const int cur = t & 1, nxt = cur ^ 1;
        if (t + 1 < nsteps) { aIssue(nxt, k + 32); bIssue(nxt, k + 32); }

        bf16x8 af[FI], bfr[FJ];
        #pragma unroll
        for (int i = 0; i < FI; i++) {
            int r = wm + i * 16 + lr;
            af[i] = *(const bf16x8*)&ldsA[cur][r * 32 + swzc(r, lg) * 8];
        }
        #pragma unroll
        for (int j = 0; j < FJ; j++) {
            int r = wn + j * 16 + lr;
            bfr[j] = *(const bf16x8*)&ldsB[cur][r * 32 + swzc(r, lg) * 8];
        }
        #pragma unroll
        for (int i = 0; i < FI; i++)
            #pragma unroll
            for (int j = 0; j < FJ; j++)
                acc[i][j] = __builtin_amdgcn_mfma_f32_16x16x32_bf16(af[i], bfr[j], acc[i][j], 0, 0, 0);

        if (t + 1 < nsteps) { aCommit(nxt, k + 32); bCommit(nxt); }
        __syncthreads();
    }

    // store: C row = m0+wm+i*16+lg*4+e, col = n0+wn+j*16+lr
    #pragma unroll
    for (int i = 0; i < FI; i++) {
        #pragma unroll
        for (int j = 0; j < FJ; j++) {
            #pragma unroll
            for (int e = 0; e < 4; e++) {
                int row = m0 + wm + i * 16 + lg * 4 + e;
                int col = n0 + wn + j * 16 + lr;
                if (row < M && col < N) {
                    float v = acc[i][j][e];
                    if constexpr (BIAS == 1) v += bias[row];
                    if constexpr (BIAS == 2) v += bias[col];
                    if constexpr (RELU) v = fmaxf(v, 0.0f);
                    if constexpr (OUTBF) ((u16*)Cp)[(size_t)row * N + col] = f2bf(v);
                    else ((float*)Cp)[(size_t)s * M * N + (size_t)row * N + col] = v;
                }
            }
        }
    }
}

// fused: sum split-K partials + residual -> LayerNorm(g,b) -> relu -> bf16 (+optional f32) out. D=256.
__global__ __launch_bounds__(256) void ln_k(
    const float* __restrict__ part, long pStride, int nPart,
    const float* __restrict__ resid, const float* __restrict__ gamma, const float* __restrict__ beta,
    u16* __restrict__ obf, float* __restrict__ of32, int M)
{
    const int w = threadIdx.x >> 6, l = threadIdx.x & 63;
    for (int row = blockIdx.x * 4 + w; row < M; row += gridDim.x * 4) {
        size_t base = (size_t)row * 256 + l * 4;
        float4 v = *(const float4*)(part + base);
        for (int s = 1; s < nPart; s++) {
            float4 u = *(const float4*)(part + (size_t)s * pStride + base);
            v.x += u.x; v.y += u.y; v.z += u.z; v.w += u.w;
        }
        float4 r = *(const float4*)(resid + base);
        v.x += r.x; v.y += r.y; v.z += r.z; v.w += r.w;
        float sum = v.x + v.y + v.z + v.w;
        float sq  = v.x*v.x + v.y*v.y + v.z*v.z + v.w*v.w;
        #pragma unroll
        for (int o = 32; o >= 1; o >>= 1) {
            sum += __shfl_xor(sum, o, 64);
            sq  += __shfl_xor(sq, o, 64);
        }
        float mu  = sum * (1.0f / 256.0f);
        float var = sq * (1.0f / 256.0f) - mu * mu;
        float sc  = rsqrtf(var + 1e-5f);
        int c = l * 4;
        float y0 = fmaxf((v.x - mu) * sc * gamma[c + 0] + beta[c + 0], 0.0f);
        float y1 = fmaxf((v.y - mu) * sc * gamma[c + 1] + beta[c + 1], 0.0f);
        float y2 = fmaxf((v.z - mu) * sc * gamma[c + 2] + beta[c + 2], 0.0f);
        float y3 = fmaxf((v.w - mu) * sc * gamma[c + 3] + beta[c + 3], 0.0f);
        u16x4 pk; pk[0] = f2bf(y0); pk[1] = f2bf(y1); pk[2] = f2bf(y2); pk[3] = f2bf(y3);
        *(u16x4*)(obf + base) = pk;
        if (of32) { float4 o4; o4.x = y0; o4.y = y1; o4.z = y2; o4.w = y3; *(float4*)(of32 + base) = o4; }
    }
}

// sum split-K partials -> f32 out + bf16 copy (embedding)
__global__ __launch_bounds__(256) void sum_k(
    const float* __restrict__ p, long pStride, int nPart,
    float* __restrict__ of, u16* __restrict__ ob, int total4)
{
    int i = blockIdx.x * 256 + threadIdx.x;
    if (i >= total4) return;
    size_t b = (size_t)i * 4;
    float4 v = *(const float4*)(p + b);
    for (int s = 1; s < nPart; s++) {
        float4 u = *(const float4*)(p + (size_t)s * pStride + b);
        v.x += u.x; v.y += u.y; v.z += u.z; v.w += u.w;
    }
    *(float4*)(of + b) = v;
    u16x4 pk; pk[0] = f2bf(v.x); pk[1] = f2bf(v.y); pk[2] = f2bf(v.z); pk[3] = f2bf(v.w);
    *(u16x4*)(ob + b) = pk;
}

// transpose + bf16-convert the 5 weight matrices. dst[o][i] = src[i][o].
__global__ __launch_bounds__(256) void prep_k(
    const float* __restrict__ s0, const float* __restrict__ s1, const float* __restrict__ s2,
    const float* __restrict__ s3, const float* __restrict__ s4,
    u16* __restrict__ d0, u16* __restrict__ d1, u16* __restrict__ d2,
    u16* __restrict__ d3, u16* __restrict__ d4)
{
    int i = blockIdx.x * 256 + threadIdx.x;
    if (i < 65536) {                       // W1 [256][256] -> [256][256]
        int o = i >> 8, ii = i & 255; d0[i] = f2bf(s0[(size_t)ii * 256 + o]);
    } else if (i < 131072) {               // W2
        int j = i - 65536; int o = j >> 8, ii = j & 255; d1[j] = f2bf(s1[(size_t)ii * 256 + o]);
    } else if (i < 163840) {               // W3 [256][128] -> [128][256]
        int j = i - 131072; int o = j >> 8, ii = j & 255; d2[j] = f2bf(s2[(size_t)ii * 128 + o]);
    } else if (i < 180224) {               // Wp1 [128][128]
        int j = i - 163840; int o = j >> 7, ii = j & 127; d3[j] = f2bf(s3[(size_t)ii * 128 + o]);
    } else if (i < 196608) {               // Wp2 [128][128]
        int j = i - 180224; int o = j >> 7, ii = j & 127; d4[j] = f2bf(s4[(size_t)ii * 128 + o]);
    }
}

extern "C" void kernel_launch(void* const* d_in, const int* in_sizes, int n_in,
                              void* d_out, int out_size, void* d_ws, size_t ws_size,
                              hipStream_t stream)
{
    if (n_in < 16) return;
    const int NN = 12000, DD = 256, EE = 128;
    const float* x   = (const float*)d_in[0];
    const float* adj = (const float*)d_in[1];
    const float* W1  = (const float*)d_in[2];
    const float* b1  = (const float*)d_in[3];
    const float* g1  = (const float*)d_in[4];
    const float* be1 = (const float*)d_in[5];
    const float* W2  = (const float*)d_in[6];
    const float* b2  = (const float*)d_in[7];
    const float* g2  = (const float*)d_in[8];
    const float* be2 = (const float*)d_in[9];
    const float* W3  = (const float*)d_in[10];
    const float* b3  = (const float*)d_in[11];
    const float* Wp1 = (const float*)d_in[12];
    const float* bp1 = (const float*)d_in[13];
    const float* Wp2 = (const float*)d_in[14];
    const float* bp2 = (const float*)d_in[15];
    float* zOut   = (float*)d_out;
    float* embOut = zOut + (size_t)NN * EE;

    char* ws = (char*)d_ws;
    size_t off = 0;
    auto alloc = [&](size_t bytes) -> void* {
        off = (off + 255) & ~(size_t)255;
        void* p = ws + off; off += bytes; return p;
    };

    const size_t adjElems = (size_t)NN * NN;
    bool cacheAdj = ws_size >= adjElems * 2 + 100000000ULL;
    u16* adjb = cacheAdj ? (u16*)alloc(adjElems * 2) : nullptr;

    u16* xW1t   = (u16*)alloc((size_t)DD * NN * 2);
    u16* hW2t   = (u16*)alloc((size_t)DD * NN * 2);
    u16* h2W3t  = (u16*)alloc((size_t)EE * NN * 2);
    u16* hbf    = (u16*)alloc((size_t)NN * DD * 2);
    float* hf32 = (float*)alloc((size_t)NN * DD * 4);
    u16* h2bf   = (u16*)alloc((size_t)NN * DD * 2);
    u16* embbf  = (u16*)alloc((size_t)NN * EE * 2);
    u16* p1bf   = (u16*)alloc((size_t)NN * EE * 2);
    u16* W1t    = (u16*)alloc(65536 * 2);
    u16* W2t    = (u16*)alloc(65536 * 2);
    u16* W3t    = (u16*)alloc(32768 * 2);
    u16* Wp1t   = (u16*)alloc(16384 * 2);
    u16* Wp2t   = (u16*)alloc(16384 * 2);

    int S = 4;
    if (off + (size_t)4 * NN * DD * 4 + 512 > ws_size) S = 1;
    float* part = (float*)alloc((size_t)S * NN * DD * 4);
    const int KCH = (S == 4) ? 3008 : 12032;

    prep_k<<<768, 256, 0, stream>>>(W1, W2, W3, Wp1, Wp2, W1t, W2t, W3t, Wp1t, Wp2t);

    // S1: xW1t[256][12000] = W1t @ x^T + b1 (bf16 out, transposed feature layout)
    gemm_k<64, 32, false, true, false, 1, false, true><<<4 * 188, 256, 0, stream>>>(
        W1t, x, xW1t, nullptr, b1, DD, NN, DD, DD, DD, 4, 188, DD);

    // P1: t1 = adj @ xW1 (fp32 adj -> cvt; dump bf16 adj for passes 2/3)
    if (cacheAdj)
        gemm_k<256, 128, true, false, true, 0, false, false><<<188 * S, 256, 0, stream>>>(
            adj, xW1t, part, adjb, nullptr, NN, DD, NN, NN, NN, 188, 1, KCH);
    else
        gemm_k<256, 128, true, false, false, 0, false, false><<<188 * S, 256, 0, stream>>>(
            adj, xW1t, part, nullptr, nullptr, NN, DD, NN, NN, NN, 188, 1, KCH);

    // E1: h = relu(LN(t1 + x)) -> hbf (bf16) + hf32 (residual)
    ln_k<<<750, 256, 0, stream>>>(part, (long)NN * DD, S, x, g1, be1, hbf, hf32, NN);

    // S2: hW2t = W2t @ h^T + b2
    gemm_k<64, 32, false, false, false, 1, false, true><<<4 * 188, 256, 0, stream>>>(
        W2t, hbf, hW2t, nullptr, b2, DD, NN, DD, DD, DD, 4, 188, DD);

    // P2: t2 = adj @ hW2
    if (cacheAdj)
        gemm_k<256, 128, false, false, false, 0, false, false><<<188 * S, 256, 0, stream>>>(
            adjb, hW2t, part, nullptr, nullptr, NN, DD, NN, NN, NN, 188, 1, KCH);
    else
        gemm_k<256, 128, true, false, false, 0, false, false><<<188 * S, 256, 0, stream>>>(
            adj, hW2t, part, nullptr, nullptr, NN, DD, NN, NN, NN, 188, 1, KCH);

    // E2: h2 = relu(LN(t2 + h))
    ln_k<<<750, 256, 0, stream>>>(part, (long)NN * DD, S, hf32, g2, be2, h2bf, nullptr, NN);

    // S3: h2W3t[128][12000] = W3t @ h2^T + b3
    gemm_k<64, 32, false, false, false, 1, false, true><<<2 * 188, 256, 0, stream>>>(
        W3t, h2bf, h2W3t, nullptr, b3, EE, NN, DD, DD, DD, 2, 188, DD);

    // P3: emb = adj @ h2W3
    if (cacheAdj)
        gemm_k<128, 64, false, false, false, 0, false, false><<<188 * S, 256, 0, stream>>>(
            adjb, h2W3t, part, nullptr, nullptr, NN, EE, NN, NN, NN, 188, 1, KCH);
    else
        gemm_k<128, 64, true, false, false, 0, false, false><<<188 * S, 256, 0, stream>>>(
            adj, h2W3t, part, nullptr, nullptr, NN, EE, NN, NN, NN, 188, 1, KCH);

    // E3: embedding out (fp32) + bf16 copy for proj head
    sum_k<<<1500, 256, 0, stream>>>(part, (long)NN * EE, S, embOut, embbf, NN * EE / 4);

    // S4: p1 = relu(emb @ Wp1 + bp1)   (natural layout, bias per col)
    gemm_k<128, 64, false, false, false, 2, true, true><<<188, 256, 0, stream>>>(
        embbf, Wp1t, p1bf, nullptr, bp1, NN, EE, EE, EE, EE, 188, 1, EE);

    // S5: z = p1 @ Wp2 + bp2 -> d_out (fp32)
    gemm_k<128, 64, false, false, false, 2, false, false><<<188, 256, 0, stream>>>(
        p1bf, Wp2t, zOut, nullptr, bp2, NN, EE, EE, EE, EE, 188, 1, EE);
}